// Round 7
// baseline (489.607 us; speedup 1.0000x reference)
//
#include <hip/hip_runtime.h>
#include <hip/hip_fp16.h>
#include <stdint.h>

typedef unsigned int   uint32;
typedef unsigned short ushort_t;
typedef _Float16 half8    __attribute__((ext_vector_type(8)));
typedef float    floatx4  __attribute__((ext_vector_type(4)));
typedef float    floatx16 __attribute__((ext_vector_type(16)));

#define DEVINL __device__ __forceinline__

#define XSTR 72    // xyz-posenc stride (64 + 8 pad), unswizzled
#define DSTR 40    // dir-posenc stride (32 + 8 pad), unswizzled
// shh: pad-free 256-short rows, XOR-swizzled 16B chunks (chunk ^= m&7):
// B-reads (32 lanes, fixed chunk, m=0..31) spread uniformly over all banks.
#define N_FRAGS 1184            // total 1KB weight fragments (32x32x16 layout)

// Packed f16 weight fragments in module-owned device memory (d_ws too small;
// round 1 showed OOB d_ws writes corrupt the harness's pristine copies).
// Rewritten every launch from restored fp32 inputs -> graph-capture safe.
__device__ __align__(16) ushort_t g_ws[(size_t)N_FRAGS * 512];

DEVINL ushort_t f2h_u(float v) { return __half_as_ushort(__float2half(v)); }

// ---------------------------------------------------------------------------
// 32x32x16 A-operand fragment: 32 feats x 16 k = 1KB. Lane L holds
// W[k = k16*16 + (L>>5)*8 + j][n = nt32*32 + (L&31)], j=0..7, as 4 dwords.
// (Generalizes the HW-verified 16x16x32 mapping m=L&15,k=(L>>4)*8+j.)
// skip63 (layer-4 concat): k<63 -> row k, k==63 -> 0, k>63 -> row k-1.
// ---------------------------------------------------------------------------
DEVINL uint4 make_frag_qword(const float* __restrict__ W, int Kr, int Nr,
                             int skip63, int k16, int nt32, int lane)
{
    const int n  = nt32*32 + (lane & 31);
    const int h5 = lane >> 5;
    uint32 pk[4];
    #pragma unroll
    for (int jj = 0; jj < 4; ++jj) {
        ushort_t h2[2];
        #pragma unroll
        for (int e = 0; e < 2; ++e) {
            const int k = k16*16 + h5*8 + jj*2 + e;
            float v = 0.f;
            if (n < Nr) {
                if (skip63) {
                    if (k != 63) { const int rr = (k < 63) ? k : (k - 1); v = W[(size_t)rr*Nr + n]; }
                } else if (k < Kr) {
                    v = W[(size_t)k*Nr + n];
                }
            }
            h2[e] = f2h_u(v);
        }
        pk[jj] = (uint32)h2[0] | ((uint32)h2[1] << 16);
    }
    return make_uint4(pk[0], pk[1], pk[2], pk[3]);
}

// prep: fp32 weights -> f16 fragments in g_ws (frag = k16*NT32 + nt32 per type)
__global__ __launch_bounds__(256) void prep_weights(
    const float* __restrict__ w0, const float* __restrict__ w1,
    const float* __restrict__ w2, const float* __restrict__ w3,
    const float* __restrict__ w4, const float* __restrict__ w5,
    const float* __restrict__ w6, const float* __restrict__ w7,
    const float* __restrict__ wf, const float* __restrict__ wsig,
    const float* __restrict__ wr1, const float* __restrict__ wr2)
{
    int gid  = blockIdx.x * 256 + threadIdx.x;
    int frag = gid >> 6;
    if (frag >= N_FRAGS) return;
    int lane = gid & 63;
    const int foff[13]  = {0,32,160,288,416,576,704,832,960,1088,1104,1176,1184};
    const int NT32[12]  = {8,8,8,8,8,8,8,8,8,1,4,1};
    const int KR[12]    = {63,256,256,256,319,256,256,256,256,256,283,128};
    const int NR[12]    = {256,256,256,256,256,256,256,256,256,1,128,3};
    const float* WP[12] = {w0,w1,w2,w3,w4,w5,w6,w7,wf,wsig,wr1,wr2};
    int t = 0;
    while (frag >= foff[t+1]) ++t;
    int fl   = frag - foff[t];
    int nt32 = fl % NT32[t];
    int k16  = fl / NT32[t];
    uint4 pk = make_frag_qword(WP[t], KR[t], NR[t], (t == 4) ? 1 : 0, k16, nt32, lane);
    *(uint4*)(g_ws + (size_t)frag*512 + lane*8) = pk;
}

// ---------------------------------------------------------------------------
// Layer (32x32x16): D[n][m] = sum_k W[k][n]*h[m][k]. A = weight frags direct
// from L2-hot g_ws; B = activation rows from LDS (swizzled shh or padded
// shx/shd). Depth-1 software pipeline on k16 steps. Per K32: 8 MFMA (was 16
// with 16x16x32) -> halves MFMA issue slots, ~20% fewer matrix-cycles.
// ---------------------------------------------------------------------------
template <int NFT, int K16T, int K16_SPLIT, int NTT32, bool SWZ0, bool SWZ1>
DEVINL void run_layer32(const ushort_t* __restrict__ wsrc,
                        const ushort_t* in0, int s0,
                        const ushort_t* in1, int s1,
                        int lane, int nt_lo32,
                        floatx16 (&acc)[2][NFT])
{
    const floatx16 vz = {0,0,0,0,0,0,0,0,0,0,0,0,0,0,0,0};
    #pragma unroll
    for (int rt2 = 0; rt2 < 2; ++rt2)
        #pragma unroll
        for (int ft = 0; ft < NFT; ++ft)
            acc[rt2][ft] = vz;

    const int ml = lane & 31, h5 = lane >> 5;
    half8 afr[2][NFT], bfr[2][2];

    auto loadk = [&](int k16, int buf) {
        const ushort_t* src; int st; bool swz; int kk;
        if (k16 < K16_SPLIT) { src = in0; st = s0; swz = SWZ0; kk = k16; }
        else                 { src = in1; st = s1; swz = SWZ1; kk = k16 - K16_SPLIT; }
        #pragma unroll
        for (int rt2 = 0; rt2 < 2; ++rt2) {
            const int m = rt2*32 + ml;
            const ushort_t* p = swz
                ? src + m*256 + (((kk*2 + h5) ^ (m & 7)) * 8)
                : src + m*st + kk*16 + h5*8;
            bfr[buf][rt2] = *(const half8*)p;
        }
        const ushort_t* wb = wsrc + (size_t)(k16*NTT32 + nt_lo32)*512 + lane*8;
        #pragma unroll
        for (int ft = 0; ft < NFT; ++ft)
            afr[buf][ft] = *(const half8*)(wb + ft*512);
    };

    loadk(0, 0);
    #pragma unroll
    for (int k16 = 0; k16 < K16T; ++k16) {
        const int cur = k16 & 1;
        if (k16 + 1 < K16T) loadk(k16 + 1, cur ^ 1);
        #pragma unroll
        for (int ft = 0; ft < NFT; ++ft)
            #pragma unroll
            for (int rt2 = 0; rt2 < 2; ++rt2)
                acc[rt2][ft] = __builtin_amdgcn_mfma_f32_32x32x16_f16(
                    afr[cur][ft], bfr[cur][rt2], acc[rt2][ft], 0, 0, 0);
    }
}

// epilogue: +bias, optional relu, pack f16, 8B swizzled store.
// 32x32 C/D (m74/m101): point m = rt2*32+(lane&31);
// feature n = (nt_lo32+ft)*32 + (reg&3) + 8*(reg>>2) + 4*(lane>>5)
// -> regs 4g..4g+3 give 4 consecutive n = 32*tile + 8g + 4*(lane>>5).
template <int NFT, bool RELU>
DEVINL void epi32(floatx16 (&acc)[2][NFT], const float* __restrict__ bias,
                  int nt_lo32, ushort_t* __restrict__ shh, int lane)
{
    const int ml = lane & 31, h5 = lane >> 5;
    #pragma unroll
    for (int rt2 = 0; rt2 < 2; ++rt2) {
        const int m = rt2*32 + ml;
        #pragma unroll
        for (int ft = 0; ft < NFT; ++ft) {
            #pragma unroll
            for (int g = 0; g < 4; ++g) {
                const int n = (nt_lo32 + ft)*32 + g*8 + h5*4;
                const floatx4 bb = *(const floatx4*)(bias + n);
                float v0 = acc[rt2][ft][g*4+0] + bb.x;
                float v1 = acc[rt2][ft][g*4+1] + bb.y;
                float v2 = acc[rt2][ft][g*4+2] + bb.z;
                float v3 = acc[rt2][ft][g*4+3] + bb.w;
                if (RELU) {
                    v0 = fmaxf(v0, 0.f); v1 = fmaxf(v1, 0.f);
                    v2 = fmaxf(v2, 0.f); v3 = fmaxf(v3, 0.f);
                }
                uint2 u;
                u.x = (uint32)f2h_u(v0) | ((uint32)f2h_u(v1) << 16);
                u.y = (uint32)f2h_u(v2) | ((uint32)f2h_u(v3) << 16);
                const int chunk = n >> 3;
                *(uint2*)(shh + m*256 + ((chunk ^ (m & 7)) * 8) + (n & 7)) = u;
            }
        }
    }
}

// (256,2): 256-reg/wave cap -> no scratch spill (demand ~160); 2 blocks/CU.
__global__ __launch_bounds__(256, 2) void nerf_fused(
    const float* __restrict__ x,
    const float* __restrict__ b0, const float* __restrict__ b1,
    const float* __restrict__ b2, const float* __restrict__ b3,
    const float* __restrict__ b4, const float* __restrict__ b5,
    const float* __restrict__ b6, const float* __restrict__ b7,
    const float* __restrict__ bf, const float* __restrict__ bsig,
    const float* __restrict__ br1, const float* __restrict__ br2,
    float* __restrict__ out)
{
    __shared__ __align__(16) ushort_t shh[64*256];    // activations, swizzled
    __shared__ __align__(16) ushort_t shx[64*XSTR];   // xyz posenc (63+pad)
    __shared__ __align__(16) ushort_t shd[64*DSTR];   // dir posenc (27+pad)

    const int tid  = threadIdx.x;
    const int wave = tid >> 6, lane = tid & 63;
    const int ml = lane & 31, h5 = lane >> 5;
    const int r0 = blockIdx.x * 64;
    const ushort_t* ws = g_ws;

    // ---- positional encoding (row = lane, job-set = wave) ----
    {
        const int r = lane;
        const float* xr = x + (size_t)(r0 + r)*6;
        for (int j = wave; j < 42; j += 4) {
            if (j < 30) {               // xyz: F=10, layout 3 + f*6 + s*3 + a
                int f = j/3, a = j%3;
                float v = xr[a] * (float)(1 << f);
                shx[r*XSTR + 3 + f*6 + a]     = f2h_u(sinf(v));
                shx[r*XSTR + 3 + f*6 + 3 + a] = f2h_u(cosf(v));
            } else {                    // dir: F=4
                int jj = j - 30, f = jj/3, a = jj%3;
                float v = xr[3+a] * (float)(1 << f);
                shd[r*DSTR + 3 + f*6 + a]     = f2h_u(sinf(v));
                shd[r*DSTR + 3 + f*6 + 3 + a] = f2h_u(cosf(v));
            }
        }
        if (wave == 0) {
            #pragma unroll
            for (int a = 0; a < 3; ++a) {
                shx[r*XSTR + a] = f2h_u(xr[a]);
                shd[r*DSTR + a] = f2h_u(xr[3+a]);
            }
            shx[r*XSTR + 63] = 0;                       // k-pad must be 0
            #pragma unroll
            for (int kq = 27; kq < 32; ++kq) shd[r*DSTR + kq] = 0;
        }
    }
    __syncthreads();

    const float* BS[8] = {b0,b1,b2,b3,b4,b5,b6,b7};
    const int WO[8] = {0,16384,81920,147456,212992,294912,360448,425984};
    const int ntl = wave * 2;           // wave's feat base in 32-col tiles

    floatx16 acc[2][2];

    // layer 0: 64(xyz) -> 256
    run_layer32<2,4,4,8,false,false>(ws + WO[0], shx, XSTR, shx, XSTR, lane, ntl, acc);
    epi32<2,true>(acc, b0, ntl, shh, lane);
    __syncthreads();

    // layers 1..7 (layer 4 = skip-concat: 4 k16 from xyz, 16 from shh)
    #pragma unroll
    for (int l = 1; l < 8; ++l) {
        if (l == 4)
            run_layer32<2,20,4,8,false,true>(ws + WO[4], shx, XSTR, shh, 256, lane, ntl, acc);
        else
            run_layer32<2,16,16,8,true,true>(ws + WO[l], shh, 256, shh, 256, lane, ntl, acc);
        __syncthreads();   // all waves done reading shh before epilogue overwrites
        epi32<2,true>(acc, BS[l], ntl, shh, lane);
        __syncthreads();   // epilogue visible before next layer reads
    }

    // sigma head: wave 0 only (barrier-free region, overlaps others' final)
    if (wave == 0) {
        floatx16 sacc[2][1];
        run_layer32<1,16,16,1,true,true>(ws + 557056, shh, 256, shh, 256, lane, 0, sacc);
        if (h5 == 0) {                 // feature 0 = reg 0, lanes 0..31
            const float bs_ = bsig[0];
            #pragma unroll
            for (int rt2 = 0; rt2 < 2; ++rt2)
                out[(size_t)(r0 + rt2*32 + ml)*4 + 3] = sacc[rt2][0][0] + bs_;
        }
    }

    // final: 256 -> 256, NO relu (barrier also covers in-flight sigma reads)
    run_layer32<2,16,16,8,true,true>(ws + 491520, shh, 256, shh, 256, lane, ntl, acc);
    __syncthreads();
    epi32<2,false>(acc, bf, ntl, shh, lane);
    __syncthreads();

    // rgb1: [final(256) | dir(27->32)] -> 128, relu
    {
        floatx16 racc[2][1];
        run_layer32<1,18,16,4,true,false>(ws + 565248, shh, 256, shd, DSTR, lane, wave, racc);
        __syncthreads();
        epi32<1,true>(racc, br1, wave, shh, lane);
        __syncthreads();
    }

    // rgb2: 128 -> 3, sigmoid, store rgb (wave 0 only)
    if (wave == 0) {
        floatx16 cacc[2][1];
        run_layer32<1,8,8,1,true,true>(ws + 602112, shh, 256, shh, 256, lane, 0, cacc);
        if (h5 == 0) {                 // feats 0,1,2 = regs 0,1,2, lanes 0..31
            const float c0 = br2[0], c1 = br2[1], c2 = br2[2];
            #pragma unroll
            for (int rt2 = 0; rt2 < 2; ++rt2) {
                const size_t o = (size_t)(r0 + rt2*32 + ml)*4;
                out[o+0] = 1.f/(1.f + expf(-(cacc[rt2][0][0] + c0)));
                out[o+1] = 1.f/(1.f + expf(-(cacc[rt2][0][1] + c1)));
                out[o+2] = 1.f/(1.f + expf(-(cacc[rt2][0][2] + c2)));
            }
        }
    }
}

extern "C" void kernel_launch(void* const* d_in, const int* in_sizes, int n_in,
                              void* d_out, int out_size, void* d_ws, size_t ws_size,
                              hipStream_t stream)
{
    const float* x  = (const float*)d_in[0];
    const float* w0 = (const float*)d_in[1];  const float* b0 = (const float*)d_in[2];
    const float* w1 = (const float*)d_in[3];  const float* b1 = (const float*)d_in[4];
    const float* w2 = (const float*)d_in[5];  const float* b2 = (const float*)d_in[6];
    const float* w3 = (const float*)d_in[7];  const float* b3 = (const float*)d_in[8];
    const float* w4 = (const float*)d_in[9];  const float* b4 = (const float*)d_in[10];
    const float* w5 = (const float*)d_in[11]; const float* b5 = (const float*)d_in[12];
    const float* w6 = (const float*)d_in[13]; const float* b6 = (const float*)d_in[14];
    const float* w7 = (const float*)d_in[15]; const float* b7 = (const float*)d_in[16];
    const float* wf = (const float*)d_in[17]; const float* bf = (const float*)d_in[18];
    const float* wsg= (const float*)d_in[19]; const float* bsg= (const float*)d_in[20];
    const float* wr1= (const float*)d_in[21]; const float* br1= (const float*)d_in[22];
    const float* wr2= (const float*)d_in[23]; const float* br2= (const float*)d_in[24];
    float* out = (float*)d_out;
    const int N = in_sizes[0] / 6;

    prep_weights<<<(N_FRAGS*64 + 255)/256, 256, 0, stream>>>(
        w0,w1,w2,w3,w4,w5,w6,w7,wf,wsg,wr1,wr2);
    nerf_fused<<<N/64, 256, 0, stream>>>(
        x, b0,b1,b2,b3,b4,b5,b6,b7, bf,bsg, br1,br2, out);
}

// Round 9
// 391.642 us; speedup vs baseline: 1.2501x; 1.2501x over previous
//
#include <hip/hip_runtime.h>
#include <hip/hip_fp16.h>
#include <stdint.h>

typedef unsigned int   uint32;
typedef unsigned short ushort_t;
typedef _Float16 half8   __attribute__((ext_vector_type(8)));
typedef float    floatx4 __attribute__((ext_vector_type(4)));

#define DEVINL __device__ __forceinline__

#define HSTR 264   // h stride (256+8 pad), x2 bytes = 528, 16B-aligned rows
#define XSTR 72    // xyz-posenc stride (64 + 8 pad)
#define DSTR 40    // dir-posenc stride (32 + 8 pad)
#define N_FRAGS 1172            // total 1KB weight fragments (16x16x32 layout)

// Packed f16 weight fragments in module-owned device memory (d_ws too small;
// round 1: OOB d_ws writes corrupt the harness's pristine copies). Rewritten
// every launch from restored fp32 inputs -> graph-capture safe. L2-resident.
__device__ __align__(16) ushort_t g_ws[(size_t)N_FRAGS * 512];

DEVINL ushort_t f2h_u(float v) { return __half_as_ushort(__float2half(v)); }

// ---------------------------------------------------------------------------
// 16x16x32 A-operand fragment: lane L (q=L>>4, cc=L&15) holds
// W[k = kt*32 + q*8 + j][n = nt*16 + cc], j=0..7, packed as 4 dwords.
// skip63 (layer-4 concat): k<63 -> row k, k==63 -> 0, k>63 -> row k-1.
// ---------------------------------------------------------------------------
DEVINL uint4 make_frag_qword(const float* __restrict__ W, int Kr, int Nr,
                             int skip63, int kt, int nt, int q, int cc)
{
    const int n = nt*16 + cc;
    uint32 pk[4];
    #pragma unroll
    for (int jj = 0; jj < 4; ++jj) {
        ushort_t h2[2];
        #pragma unroll
        for (int e = 0; e < 2; ++e) {
            const int k = kt*32 + q*8 + jj*2 + e;
            float v = 0.f;
            if (n < Nr) {
                if (skip63) {
                    if (k != 63) { const int rr = (k < 63) ? k : (k - 1); v = W[(size_t)rr*Nr + n]; }
                } else if (k < Kr) {
                    v = W[(size_t)k*Nr + n];
                }
            }
            h2[e] = f2h_u(v);
        }
        pk[jj] = (uint32)h2[0] | ((uint32)h2[1] << 16);
    }
    return make_uint4(pk[0], pk[1], pk[2], pk[3]);
}

__global__ __launch_bounds__(256) void prep_weights(
    const float* __restrict__ w0, const float* __restrict__ w1,
    const float* __restrict__ w2, const float* __restrict__ w3,
    const float* __restrict__ w4, const float* __restrict__ w5,
    const float* __restrict__ w6, const float* __restrict__ w7,
    const float* __restrict__ wf, const float* __restrict__ wsig,
    const float* __restrict__ wr1, const float* __restrict__ wr2)
{
    int gid  = blockIdx.x * 256 + threadIdx.x;
    int frag = gid >> 6;
    if (frag >= N_FRAGS) return;
    int lane = gid & 63;
    const int foff[13] = {0,32,160,288,416,576,704,832,960,1088,1096,1168,1172};
    const int NT[12]   = {16,16,16,16,16,16,16,16,16,1,8,1};
    const int KR[12]   = {63,256,256,256,319,256,256,256,256,256,283,128};
    const int NR[12]   = {256,256,256,256,256,256,256,256,256,1,128,3};
    const float* WP[12] = {w0,w1,w2,w3,w4,w5,w6,w7,wf,wsig,wr1,wr2};
    int t = 0;
    while (frag >= foff[t+1]) ++t;
    int fl = frag - foff[t];
    int nt = fl % NT[t];
    int kt = fl / NT[t];
    uint4 pk = make_frag_qword(WP[t], KR[t], NR[t], (t == 4) ? 1 : 0, kt, nt,
                               lane >> 4, lane & 15);
    *(uint4*)(g_ws + (size_t)frag*512 + lane*8) = pk;
}

// ---------------------------------------------------------------------------
// Layer: D[n][m] = sum_k W[k][n] * h[m][k]. A-frags direct from L2-hot g_ws,
// B-frags from LDS; both depth-1 pipelined. Strides are template constants so
// all B addresses fold into ds_read offset immediates (one vaddr per source).
// First kt uses binit (bias, wave-uniform per (q,reg,nt)) as the MFMA
// C-operand: no accumulator zero-init, no epilogue bias add.
// ---------------------------------------------------------------------------
template <int NT_W, int KT, int KT_SPLIT, int NTT, int S0, int S1>
DEVINL void run_layer(const ushort_t* __restrict__ wsrc,
                      const ushort_t* __restrict__ in0,
                      const ushort_t* __restrict__ in1,
                      int lane, int q, int cc, int nt_lo,
                      const floatx4 (&binit)[NT_W], floatx4 (&acc)[4][NT_W])
{
    half8 bfr[2][4];
    half8 afr[2][NT_W];

    auto loadk = [&](int kt, int buf) {
        #pragma unroll
        for (int rt = 0; rt < 4; ++rt) {
            const ushort_t* p = (kt < KT_SPLIT)
                ? in0 + (rt*16 + cc)*S0 + kt*32 + q*8
                : in1 + (rt*16 + cc)*S1 + (kt - KT_SPLIT)*32 + q*8;
            bfr[buf][rt] = *(const half8*)p;
        }
        const ushort_t* wb = wsrc + (size_t)(kt*NTT + nt_lo)*512 + lane*8;
        #pragma unroll
        for (int nt = 0; nt < NT_W; ++nt)
            afr[buf][nt] = *(const half8*)(wb + nt*512);
    };

    loadk(0, 0);
    #pragma unroll
    for (int kt = 0; kt < KT; ++kt) {
        const int cur = kt & 1;
        if (kt + 1 < KT) loadk(kt + 1, cur ^ 1);
        #pragma unroll
        for (int nt = 0; nt < NT_W; ++nt)
            #pragma unroll
            for (int rt = 0; rt < 4; ++rt)
                acc[rt][nt] = __builtin_amdgcn_mfma_f32_16x16x32_f16(
                    afr[cur][nt], bfr[cur][rt],
                    (kt == 0) ? binit[nt] : acc[rt][nt], 0, 0, 0);
    }
}

// epilogue: optional relu, pack to f16 (cvt_pkrtz), 8B LDS store per (rt,nt).
// D layout: m = rt*16 + (lane&15), features n..n+3 = (nt_lo+nt)*16 + q*4 + reg
template <int NT_W, bool RELU>
DEVINL void epilogue_h(floatx4 (&acc)[4][NT_W], int nt_lo,
                       ushort_t* __restrict__ shh, int q, int cc)
{
    #pragma unroll
    for (int rt = 0; rt < 4; ++rt) {
        const int m = rt*16 + cc;
        #pragma unroll
        for (int nt = 0; nt < NT_W; ++nt) {
            const int n = (nt_lo + nt)*16 + q*4;
            floatx4 v = acc[rt][nt];
            if (RELU) {
                v.x = fmaxf(v.x, 0.f); v.y = fmaxf(v.y, 0.f);
                v.z = fmaxf(v.z, 0.f); v.w = fmaxf(v.w, 0.f);
            }
            uint2 u;
            u.x = __builtin_bit_cast(uint32, __builtin_amdgcn_cvt_pkrtz(v.x, v.y));
            u.y = __builtin_bit_cast(uint32, __builtin_amdgcn_cvt_pkrtz(v.z, v.w));
            *(uint2*)(shh + (size_t)m*HSTR + n) = u;
        }
    }
}

// (256,2): 256-reg/wave cap -> no scratch spill; 2 blocks/CU (LDS 48.1KB).
__global__ __launch_bounds__(256, 2) void nerf_fused(
    const float* __restrict__ x,
    const float* __restrict__ b0, const float* __restrict__ b1,
    const float* __restrict__ b2, const float* __restrict__ b3,
    const float* __restrict__ b4, const float* __restrict__ b5,
    const float* __restrict__ b6, const float* __restrict__ b7,
    const float* __restrict__ bf, const float* __restrict__ bsig,
    const float* __restrict__ br1, const float* __restrict__ br2,
    float* __restrict__ out)
{
    __shared__ __align__(16) ushort_t shh[64*HSTR];   // activations, f16
    __shared__ __align__(16) ushort_t shx[64*XSTR];   // xyz posenc (63+pad)
    __shared__ __align__(16) ushort_t shd[64*DSTR];   // dir posenc (27+pad)

    const int tid  = threadIdx.x;
    const int wave = tid >> 6, lane = tid & 63;
    const int q = lane >> 4, cc = lane & 15;
    const int r0 = blockIdx.x * 64;
    const ushort_t* ws = g_ws;

    // ---- positional encoding (row = lane, job-set = wave) ----
    {
        const int r = lane;
        const float* xr = x + (size_t)(r0 + r)*6;
        for (int j = wave; j < 42; j += 4) {
            if (j < 30) {               // xyz: F=10, layout 3 + f*6 + s*3 + a
                int f = j/3, a = j%3;
                float v = xr[a] * (float)(1 << f);
                shx[r*XSTR + 3 + f*6 + a]     = f2h_u(sinf(v));
                shx[r*XSTR + 3 + f*6 + 3 + a] = f2h_u(cosf(v));
            } else {                    // dir: F=4
                int jj = j - 30, f = jj/3, a = jj%3;
                float v = xr[3+a] * (float)(1 << f);
                shd[r*DSTR + 3 + f*6 + a]     = f2h_u(sinf(v));
                shd[r*DSTR + 3 + f*6 + 3 + a] = f2h_u(cosf(v));
            }
        }
        if (wave == 0) {
            #pragma unroll
            for (int a = 0; a < 3; ++a) {
                shx[r*XSTR + a] = f2h_u(xr[a]);
                shd[r*DSTR + a] = f2h_u(xr[3+a]);
            }
            shx[r*XSTR + 63] = 0;                       // k-pad must be 0
            #pragma unroll
            for (int kq = 27; kq < 32; ++kq) shd[r*DSTR + kq] = 0;
        }
    }
    __syncthreads();

    const float* BS[8] = {b0,b1,b2,b3,b4,b5,b6,b7};
    const int WO[8] = {0,16384,81920,147456,212992,294912,360448,425984};
    const int nt_lo4 = wave * 4;
    const floatx4 vz = {0.f, 0.f, 0.f, 0.f};

    floatx4 acc[4][4];
    floatx4 bl[4];

    // layer 0: 64(xyz) -> 256
    #pragma unroll
    for (int nt = 0; nt < 4; ++nt)
        bl[nt] = *(const floatx4*)(b0 + (nt_lo4 + nt)*16 + q*4);
    run_layer<4,2,2,16,XSTR,XSTR>(ws + WO[0], shx, shx, lane, q, cc, nt_lo4, bl, acc);
    epilogue_h<4,true>(acc, nt_lo4, shh, q, cc);
    __syncthreads();

    // layers 1..7 (layer 4 = skip-concat: 2 kt from xyz, 8 kt from h)
    #pragma unroll
    for (int l = 1; l < 8; ++l) {
        #pragma unroll
        for (int nt = 0; nt < 4; ++nt)
            bl[nt] = *(const floatx4*)(BS[l] + (nt_lo4 + nt)*16 + q*4);
        if (l == 4)
            run_layer<4,10,2,16,XSTR,HSTR>(ws + WO[4], shx, shh, lane, q, cc, nt_lo4, bl, acc);
        else
            run_layer<4,8,8,16,HSTR,HSTR>(ws + WO[l], shh, shh, lane, q, cc, nt_lo4, bl, acc);
        __syncthreads();   // all waves done reading shh before epilogue overwrites
        epilogue_h<4,true>(acc, nt_lo4, shh, q, cc);
        __syncthreads();   // epilogue visible before next layer reads
    }

    // sigma head: wave 0 only (barrier-free region, overlaps others' final)
    if (wave == 0) {
        floatx4 sacc[4][1];
        const floatx4 bz[1] = {vz};
        run_layer<1,8,8,1,HSTR,HSTR>(ws + 557056, shh, shh, lane, q, cc, 0, bz, sacc);
        if (q == 0) {                  // feature 0 lives in reg 0 of quad 0
            const float bs_ = bsig[0];
            #pragma unroll
            for (int rt = 0; rt < 4; ++rt)
                out[(size_t)(r0 + rt*16 + cc)*4 + 3] = sacc[rt][0].x + bs_;
        }
    }

    // final: 256 -> 256, NO relu (barrier also covers in-flight sigma reads)
    #pragma unroll
    for (int nt = 0; nt < 4; ++nt)
        bl[nt] = *(const floatx4*)(bf + (nt_lo4 + nt)*16 + q*4);
    run_layer<4,8,8,16,HSTR,HSTR>(ws + 491520, shh, shh, lane, q, cc, nt_lo4, bl, acc);
    __syncthreads();
    epilogue_h<4,false>(acc, nt_lo4, shh, q, cc);
    __syncthreads();

    // rgb1: [final(256) | dir(27->32)] -> 128, relu
    {
        floatx4 racc[4][2];
        floatx4 bl2[2];
        #pragma unroll
        for (int nt = 0; nt < 2; ++nt)
            bl2[nt] = *(const floatx4*)(br1 + (wave*2 + nt)*16 + q*4);
        run_layer<2,9,8,8,HSTR,DSTR>(ws + 561152, shh, shd, lane, q, cc, wave*2, bl2, racc);
        __syncthreads();
        epilogue_h<2,true>(racc, wave*2, shh, q, cc);
        __syncthreads();
    }

    // rgb2: 128 -> 3, sigmoid, store rgb (wave 0 only)
    if (wave == 0) {
        floatx4 cacc[4][1];
        const floatx4 bz[1] = {vz};
        run_layer<1,4,4,1,HSTR,HSTR>(ws + 598016, shh, shh, lane, q, cc, 0, bz, cacc);
        if (q == 0) {
            const float c0 = br2[0], c1 = br2[1], c2 = br2[2];
            #pragma unroll
            for (int rt = 0; rt < 4; ++rt) {
                const size_t o = (size_t)(r0 + rt*16 + cc)*4;
                out[o+0] = 1.f/(1.f + expf(-(cacc[rt][0].x + c0)));
                out[o+1] = 1.f/(1.f + expf(-(cacc[rt][0].y + c1)));
                out[o+2] = 1.f/(1.f + expf(-(cacc[rt][0].z + c2)));
            }
        }
    }
}

extern "C" void kernel_launch(void* const* d_in, const int* in_sizes, int n_in,
                              void* d_out, int out_size, void* d_ws, size_t ws_size,
                              hipStream_t stream)
{
    const float* x  = (const float*)d_in[0];
    const float* w0 = (const float*)d_in[1];  const float* b0 = (const float*)d_in[2];
    const float* w1 = (const float*)d_in[3];  const float* b1 = (const float*)d_in[4];
    const float* w2 = (const float*)d_in[5];  const float* b2 = (const float*)d_in[6];
    const float* w3 = (const float*)d_in[7];  const float* b3 = (const float*)d_in[8];
    const float* w4 = (const float*)d_in[9];  const float* b4 = (const float*)d_in[10];
    const float* w5 = (const float*)d_in[11]; const float* b5 = (const float*)d_in[12];
    const float* w6 = (const float*)d_in[13]; const float* b6 = (const float*)d_in[14];
    const float* w7 = (const float*)d_in[15]; const float* b7 = (const float*)d_in[16];
    const float* wf = (const float*)d_in[17]; const float* bf = (const float*)d_in[18];
    const float* wsg= (const float*)d_in[19]; const float* bsg= (const float*)d_in[20];
    const float* wr1= (const float*)d_in[21]; const float* br1= (const float*)d_in[22];
    const float* wr2= (const float*)d_in[23]; const float* br2= (const float*)d_in[24];
    float* out = (float*)d_out;
    const int N = in_sizes[0] / 6;

    prep_weights<<<(N_FRAGS*64 + 255)/256, 256, 0, stream>>>(
        w0,w1,w2,w3,w4,w5,w6,w7,wf,wsg,wr1,wr2);
    nerf_fused<<<N/64, 256, 0, stream>>>(
        x, b0,b1,b2,b3,b4,b5,b6,b7, bf,bsg, br1,br2, out);
}

// Round 10
// 387.494 us; speedup vs baseline: 1.2635x; 1.0107x over previous
//
#include <hip/hip_runtime.h>
#include <hip/hip_fp16.h>
#include <stdint.h>

typedef unsigned int   uint32;
typedef unsigned short ushort_t;
typedef _Float16 half8   __attribute__((ext_vector_type(8)));
typedef float    floatx4 __attribute__((ext_vector_type(4)));

#define DEVINL __device__ __forceinline__

#define HSTR 264   // h stride (256+8 pad), x2 bytes = 528, 16B-aligned rows
#define XSTR 72    // xyz-posenc stride (64 + 8 pad)
#define DSTR 40    // dir-posenc stride (32 + 8 pad)
#define N_FRAGS 1172            // total 1KB weight fragments (16x16x32 layout)

// Packed f16 weight fragments in module-owned device memory (d_ws too small;
// round 1: OOB d_ws writes corrupt the harness's pristine copies). Rewritten
// every launch from restored fp32 inputs -> graph-capture safe. L2-resident.
__device__ __align__(16) ushort_t g_ws[(size_t)N_FRAGS * 512];

DEVINL ushort_t f2h_u(float v) { return __half_as_ushort(__float2half(v)); }

// ---------------------------------------------------------------------------
// 16x16x32 A-operand fragment: lane L (q=L>>4, cc=L&15) holds
// W[k = kt*32 + q*8 + j][n = nt*16 + cc], j=0..7, packed as 4 dwords.
// skip63 (layer-4 concat): k<63 -> row k, k==63 -> 0, k>63 -> row k-1.
// ---------------------------------------------------------------------------
DEVINL uint4 make_frag_qword(const float* __restrict__ W, int Kr, int Nr,
                             int skip63, int kt, int nt, int q, int cc)
{
    const int n = nt*16 + cc;
    uint32 pk[4];
    #pragma unroll
    for (int jj = 0; jj < 4; ++jj) {
        ushort_t h2[2];
        #pragma unroll
        for (int e = 0; e < 2; ++e) {
            const int k = kt*32 + q*8 + jj*2 + e;
            float v = 0.f;
            if (n < Nr) {
                if (skip63) {
                    if (k != 63) { const int rr = (k < 63) ? k : (k - 1); v = W[(size_t)rr*Nr + n]; }
                } else if (k < Kr) {
                    v = W[(size_t)k*Nr + n];
                }
            }
            h2[e] = f2h_u(v);
        }
        pk[jj] = (uint32)h2[0] | ((uint32)h2[1] << 16);
    }
    return make_uint4(pk[0], pk[1], pk[2], pk[3]);
}

__global__ __launch_bounds__(256) void prep_weights(
    const float* __restrict__ w0, const float* __restrict__ w1,
    const float* __restrict__ w2, const float* __restrict__ w3,
    const float* __restrict__ w4, const float* __restrict__ w5,
    const float* __restrict__ w6, const float* __restrict__ w7,
    const float* __restrict__ wf, const float* __restrict__ wsig,
    const float* __restrict__ wr1, const float* __restrict__ wr2)
{
    int gid  = blockIdx.x * 256 + threadIdx.x;
    int frag = gid >> 6;
    if (frag >= N_FRAGS) return;
    int lane = gid & 63;
    const int foff[13] = {0,32,160,288,416,576,704,832,960,1088,1096,1168,1172};
    const int NT[12]   = {16,16,16,16,16,16,16,16,16,1,8,1};
    const int KR[12]   = {63,256,256,256,319,256,256,256,256,256,283,128};
    const int NR[12]   = {256,256,256,256,256,256,256,256,256,1,128,3};
    const float* WP[12] = {w0,w1,w2,w3,w4,w5,w6,w7,wf,wsig,wr1,wr2};
    int t = 0;
    while (frag >= foff[t+1]) ++t;
    int fl = frag - foff[t];
    int nt = fl % NT[t];
    int kt = fl / NT[t];
    uint4 pk = make_frag_qword(WP[t], KR[t], NR[t], (t == 4) ? 1 : 0, kt, nt,
                               lane >> 4, lane & 15);
    *(uint4*)(g_ws + (size_t)frag*512 + lane*8) = pk;
}

// ---------------------------------------------------------------------------
// Layer: D[n][m] = sum_k W[k][n] * h[m][k]. A-frags direct from L2-hot g_ws,
// B-frags from LDS; both depth-1 pipelined. Strides are template constants so
// all B addresses fold into ds_read offset immediates (one vaddr per source).
// First kt uses binit (bias, wave-uniform per (q,reg,nt)) as the MFMA
// C-operand: no accumulator zero-init, no epilogue bias add.
// ---------------------------------------------------------------------------
template <int NT_W, int KT, int KT_SPLIT, int NTT, int S0, int S1>
DEVINL void run_layer(const ushort_t* __restrict__ wsrc,
                      const ushort_t* __restrict__ in0,
                      const ushort_t* __restrict__ in1,
                      int lane, int q, int cc, int nt_lo,
                      const floatx4 (&binit)[NT_W], floatx4 (&acc)[4][NT_W])
{
    half8 bfr[2][4];
    half8 afr[2][NT_W];

    auto loadk = [&](int kt, int buf) {
        #pragma unroll
        for (int rt = 0; rt < 4; ++rt) {
            const ushort_t* p = (kt < KT_SPLIT)
                ? in0 + (rt*16 + cc)*S0 + kt*32 + q*8
                : in1 + (rt*16 + cc)*S1 + (kt - KT_SPLIT)*32 + q*8;
            bfr[buf][rt] = *(const half8*)p;
        }
        const ushort_t* wb = wsrc + (size_t)(kt*NTT + nt_lo)*512 + lane*8;
        #pragma unroll
        for (int nt = 0; nt < NT_W; ++nt)
            afr[buf][nt] = *(const half8*)(wb + nt*512);
    };

    loadk(0, 0);
    #pragma unroll
    for (int kt = 0; kt < KT; ++kt) {
        const int cur = kt & 1;
        if (kt + 1 < KT) loadk(kt + 1, cur ^ 1);
        #pragma unroll
        for (int nt = 0; nt < NT_W; ++nt)
            #pragma unroll
            for (int rt = 0; rt < 4; ++rt)
                acc[rt][nt] = __builtin_amdgcn_mfma_f32_16x16x32_f16(
                    afr[cur][nt], bfr[cur][rt],
                    (kt == 0) ? binit[nt] : acc[rt][nt], 0, 0, 0);
    }
}

// epilogue: optional relu, pack to f16 (cvt_pkrtz), 8B LDS store per (rt,nt).
// D layout: m = rt*16 + (lane&15), features n..n+3 = (nt_lo+nt)*16 + q*4 + reg
template <int NT_W, bool RELU>
DEVINL void epilogue_h(floatx4 (&acc)[4][NT_W], int nt_lo,
                       ushort_t* __restrict__ shh, int q, int cc)
{
    #pragma unroll
    for (int rt = 0; rt < 4; ++rt) {
        const int m = rt*16 + cc;
        #pragma unroll
        for (int nt = 0; nt < NT_W; ++nt) {
            const int n = (nt_lo + nt)*16 + q*4;
            floatx4 v = acc[rt][nt];
            if (RELU) {
                v.x = fmaxf(v.x, 0.f); v.y = fmaxf(v.y, 0.f);
                v.z = fmaxf(v.z, 0.f); v.w = fmaxf(v.w, 0.f);
            }
            uint2 u;
            u.x = __builtin_bit_cast(uint32, __builtin_amdgcn_cvt_pkrtz(v.x, v.y));
            u.y = __builtin_bit_cast(uint32, __builtin_amdgcn_cvt_pkrtz(v.z, v.w));
            *(uint2*)(shh + (size_t)m*HSTR + n) = u;
        }
    }
}

// (256,3): 168-reg/wave cap; demand = 84 arch (measured r9) + 64 acc = 148
// -> fits, no spill (round-4's spill was at 84+84=168 with fatter live state).
// 3 blocks/CU (LDS 144KB/CU), 3 waves/SIMD to cover MFMA-pipe bubbles.
__global__ __launch_bounds__(256, 3) void nerf_fused(
    const float* __restrict__ x,
    const float* __restrict__ b0, const float* __restrict__ b1,
    const float* __restrict__ b2, const float* __restrict__ b3,
    const float* __restrict__ b4, const float* __restrict__ b5,
    const float* __restrict__ b6, const float* __restrict__ b7,
    const float* __restrict__ bf, const float* __restrict__ bsig,
    const float* __restrict__ br1, const float* __restrict__ br2,
    float* __restrict__ out)
{
    __shared__ __align__(16) ushort_t shh[64*HSTR];   // activations, f16
    __shared__ __align__(16) ushort_t shx[64*XSTR];   // xyz posenc (63+pad)
    __shared__ __align__(16) ushort_t shd[64*DSTR];   // dir posenc (27+pad)

    const int tid  = threadIdx.x;
    const int wave = tid >> 6, lane = tid & 63;
    const int q = lane >> 4, cc = lane & 15;
    const int r0 = blockIdx.x * 64;
    const ushort_t* ws = g_ws;

    // ---- positional encoding (row = lane, job-set = wave) ----
    {
        const int r = lane;
        const float* xr = x + (size_t)(r0 + r)*6;
        for (int j = wave; j < 42; j += 4) {
            if (j < 30) {               // xyz: F=10, layout 3 + f*6 + s*3 + a
                int f = j/3, a = j%3;
                float v = xr[a] * (float)(1 << f);
                shx[r*XSTR + 3 + f*6 + a]     = f2h_u(sinf(v));
                shx[r*XSTR + 3 + f*6 + 3 + a] = f2h_u(cosf(v));
            } else {                    // dir: F=4
                int jj = j - 30, f = jj/3, a = jj%3;
                float v = xr[3+a] * (float)(1 << f);
                shd[r*DSTR + 3 + f*6 + a]     = f2h_u(sinf(v));
                shd[r*DSTR + 3 + f*6 + 3 + a] = f2h_u(cosf(v));
            }
        }
        if (wave == 0) {
            #pragma unroll
            for (int a = 0; a < 3; ++a) {
                shx[r*XSTR + a] = f2h_u(xr[a]);
                shd[r*DSTR + a] = f2h_u(xr[3+a]);
            }
            shx[r*XSTR + 63] = 0;                       // k-pad must be 0
            #pragma unroll
            for (int kq = 27; kq < 32; ++kq) shd[r*DSTR + kq] = 0;
        }
    }
    __syncthreads();

    const float* BS[8] = {b0,b1,b2,b3,b4,b5,b6,b7};
    const int WO[8] = {0,16384,81920,147456,212992,294912,360448,425984};
    const int nt_lo4 = wave * 4;
    const floatx4 vz = {0.f, 0.f, 0.f, 0.f};

    floatx4 acc[4][4];
    floatx4 bl[4];

    // layer 0: 64(xyz) -> 256
    #pragma unroll
    for (int nt = 0; nt < 4; ++nt)
        bl[nt] = *(const floatx4*)(b0 + (nt_lo4 + nt)*16 + q*4);
    run_layer<4,2,2,16,XSTR,XSTR>(ws + WO[0], shx, shx, lane, q, cc, nt_lo4, bl, acc);
    epilogue_h<4,true>(acc, nt_lo4, shh, q, cc);
    __syncthreads();

    // layers 1..7 (layer 4 = skip-concat: 2 kt from xyz, 8 kt from h)
    #pragma unroll
    for (int l = 1; l < 8; ++l) {
        #pragma unroll
        for (int nt = 0; nt < 4; ++nt)
            bl[nt] = *(const floatx4*)(BS[l] + (nt_lo4 + nt)*16 + q*4);
        if (l == 4)
            run_layer<4,10,2,16,XSTR,HSTR>(ws + WO[4], shx, shh, lane, q, cc, nt_lo4, bl, acc);
        else
            run_layer<4,8,8,16,HSTR,HSTR>(ws + WO[l], shh, shh, lane, q, cc, nt_lo4, bl, acc);
        __syncthreads();   // all waves done reading shh before epilogue overwrites
        epilogue_h<4,true>(acc, nt_lo4, shh, q, cc);
        __syncthreads();   // epilogue visible before next layer reads
    }

    // sigma head: wave 0 only (barrier-free region, overlaps others' final)
    if (wave == 0) {
        floatx4 sacc[4][1];
        const floatx4 bz[1] = {vz};
        run_layer<1,8,8,1,HSTR,HSTR>(ws + 557056, shh, shh, lane, q, cc, 0, bz, sacc);
        if (q == 0) {                  // feature 0 lives in reg 0 of quad 0
            const float bs_ = bsig[0];
            #pragma unroll
            for (int rt = 0; rt < 4; ++rt)
                out[(size_t)(r0 + rt*16 + cc)*4 + 3] = sacc[rt][0].x + bs_;
        }
    }

    // final: 256 -> 256, NO relu (barrier also covers in-flight sigma reads)
    #pragma unroll
    for (int nt = 0; nt < 4; ++nt)
        bl[nt] = *(const floatx4*)(bf + (nt_lo4 + nt)*16 + q*4);
    run_layer<4,8,8,16,HSTR,HSTR>(ws + 491520, shh, shh, lane, q, cc, nt_lo4, bl, acc);
    __syncthreads();
    epilogue_h<4,false>(acc, nt_lo4, shh, q, cc);
    __syncthreads();

    // rgb1: [final(256) | dir(27->32)] -> 128, relu
    {
        floatx4 racc[4][2];
        floatx4 bl2[2];
        #pragma unroll
        for (int nt = 0; nt < 2; ++nt)
            bl2[nt] = *(const floatx4*)(br1 + (wave*2 + nt)*16 + q*4);
        run_layer<2,9,8,8,HSTR,DSTR>(ws + 561152, shh, shd, lane, q, cc, wave*2, bl2, racc);
        __syncthreads();
        epilogue_h<2,true>(racc, wave*2, shh, q, cc);
        __syncthreads();
    }

    // rgb2: 128 -> 3, sigmoid, store rgb (wave 0 only)
    if (wave == 0) {
        floatx4 cacc[4][1];
        const floatx4 bz[1] = {vz};
        run_layer<1,4,4,1,HSTR,HSTR>(ws + 598016, shh, shh, lane, q, cc, 0, bz, cacc);
        if (q == 0) {
            const float c0 = br2[0], c1 = br2[1], c2 = br2[2];
            #pragma unroll
            for (int rt = 0; rt < 4; ++rt) {
                const size_t o = (size_t)(r0 + rt*16 + cc)*4;
                out[o+0] = 1.f/(1.f + expf(-(cacc[rt][0].x + c0)));
                out[o+1] = 1.f/(1.f + expf(-(cacc[rt][0].y + c1)));
                out[o+2] = 1.f/(1.f + expf(-(cacc[rt][0].z + c2)));
            }
        }
    }
}

extern "C" void kernel_launch(void* const* d_in, const int* in_sizes, int n_in,
                              void* d_out, int out_size, void* d_ws, size_t ws_size,
                              hipStream_t stream)
{
    const float* x  = (const float*)d_in[0];
    const float* w0 = (const float*)d_in[1];  const float* b0 = (const float*)d_in[2];
    const float* w1 = (const float*)d_in[3];  const float* b1 = (const float*)d_in[4];
    const float* w2 = (const float*)d_in[5];  const float* b2 = (const float*)d_in[6];
    const float* w3 = (const float*)d_in[7];  const float* b3 = (const float*)d_in[8];
    const float* w4 = (const float*)d_in[9];  const float* b4 = (const float*)d_in[10];
    const float* w5 = (const float*)d_in[11]; const float* b5 = (const float*)d_in[12];
    const float* w6 = (const float*)d_in[13]; const float* b6 = (const float*)d_in[14];
    const float* w7 = (const float*)d_in[15]; const float* b7 = (const float*)d_in[16];
    const float* wf = (const float*)d_in[17]; const float* bf = (const float*)d_in[18];
    const float* wsg= (const float*)d_in[19]; const float* bsg= (const float*)d_in[20];
    const float* wr1= (const float*)d_in[21]; const float* br1= (const float*)d_in[22];
    const float* wr2= (const float*)d_in[23]; const float* br2= (const float*)d_in[24];
    float* out = (float*)d_out;
    const int N = in_sizes[0] / 6;

    prep_weights<<<(N_FRAGS*64 + 255)/256, 256, 0, stream>>>(
        w0,w1,w2,w3,w4,w5,w6,w7,wf,wsg,wr1,wr2);
    nerf_fused<<<N/64, 256, 0, stream>>>(
        x, b0,b1,b2,b3,b4,b5,b6,b7, bf,bsg, br1,br2, out);
}